// Round 4
// baseline (239.518 us; speedup 1.0000x reference)
//
#include <hip/hip_runtime.h>

// Izhikevich neuron scan. x: [B=16, C=64, N=1024, T=32] f32, T contiguous.
// 1M independent neurons (= 16384 tiles of 64 neurons), 32-step recurrence.
//
// R3 post-mortem: one-shot waves (load -> wait -> LDS -> compute -> store ->
// die) keep loads in flight only ~30% of wave lifetime -> ~4 KB avg
// outstanding/CU -> 2.5 TB/s latency-bound plateau, identical in R2 and R3.
// fillBuffer hits 6.6 TB/s on the same buffers; m13 float4 copy 6.29 TB/s.
//
// R4: persistent waves, grid-stride 4 tiles/wave, register double-buffer.
// Per iteration: scatter tile i regs->LDS, issue tile i+1's 8 global loads,
// then gather/compute/store tile i. Loads stay outstanding through the whole
// LDS+compute phase: ~16 waves/CU x 8 KB in flight -> HBM-BW regime.
// 4 waves/block with wave-private 8 KB LDS slices, NO barriers.
// LDS: 128 B rows (64 rows x 32 floats), XOR swizzle group^(row&7) ->
// per-octet bank-group permutation, conflict-free b128, zero padding.
//
// Numerics: bit-exact f32 replication of the numpy reference (contract off,
// left-assoc order, literal spike-blend). LDS round-trip preserves bits.

#define T_STEPS 32
#define WPB 4                 // waves per block (independent, barrier-free)
#define TPB (WPB * 64)
#define ITERS 4               // tiles per wave

__global__ __launch_bounds__(TPB) void izhikevich_kernel(
    const float* __restrict__ x,
    const float* __restrict__ pa,
    const float* __restrict__ pb,
    const float* __restrict__ pc,
    const float* __restrict__ pd,
    float* __restrict__ out,
    int stride_tiles)
{
#pragma clang fp contract(off)
    __shared__ float lds_all[WPB * 2048];          // 8 KB per wave
    const int lane = threadIdx.x & 63;
    const int wave = threadIdx.x >> 6;
    float* __restrict__ L = &lds_all[wave * 2048]; // wave-private slice

    const int wid = blockIdx.x * WPB + wave;

    const float a = pa[0];
    const float b = pb[0];
    const float c = pc[0];
    const float d = pd[0];

    const float4* __restrict__ xin = reinterpret_cast<const float4*>(x);
    float4* __restrict__ op = reinterpret_cast<float4*>(out);

    // LDS addressing. Tile = 64 neurons x 32 times; row n = neuron, 32 floats
    // (128 B). float4 slot g (times 4g..4g+3) stored at group g ^ (n&7).
    // Scatter/readback: instr k, lane -> n = k*8 + lane/8, g = lane%8;
    // n&7 = lane/8, so swizzle is k-independent.
    const int oct = lane >> 3;                 // 0..7
    const int grp = lane & 7;                  // 0..7
    const int scat_base = oct * 32 + ((grp ^ oct) << 2);   // + k*256
    const int row_base = lane * 32;            // own-row base for compute

    float4 buf[2][8];

    // Prefetch tile 0 (tile base in float4s: tile * 512).
    {
        const size_t tb = (size_t)wid * 512;
#pragma unroll
        for (int k = 0; k < 8; ++k) buf[0][k] = xin[tb + k * 64 + lane];
    }

#pragma unroll
    for (int i = 0; i < ITERS; ++i) {
        const int cur = i & 1;
        const int nxt = cur ^ 1;
        const size_t tile = (size_t)wid + (size_t)i * (size_t)stride_tiles;

        // ---- scatter current tile regs -> LDS (swizzled, conflict-free) --
#pragma unroll
        for (int k = 0; k < 8; ++k)
            *reinterpret_cast<float4*>(&L[k * 256 + scat_base]) = buf[cur][k];

        // ---- issue next tile's global loads (overlap with LDS + compute) -
        if (i + 1 < ITERS) {
            const size_t tb = (tile + (size_t)stride_tiles) * 512;
#pragma unroll
            for (int k = 0; k < 8; ++k) buf[nxt][k] = xin[tb + k * 64 + lane];
        }

        // ---- recurrence on own row, 4 timesteps per b128 chunk, in-place -
        float v = 0.0f;
        float u = 0.0f;
#pragma unroll
        for (int q = 0; q < 8; ++q) {
            float* p = &L[row_base + ((q ^ grp) << 2)];
            const float4 xv = *reinterpret_cast<const float4*>(p);
            const float xq[4] = {xv.x, xv.y, xv.z, xv.w};
            float4 sp;
            float* sf = reinterpret_cast<float*>(&sp);
#pragma unroll
            for (int j = 0; j < 4; ++j) {
                const float xt = xq[j];
                // dv = 0.04*v*v + 5.0*v + 140.0 - u + x_t  (left-assoc)
                const float t1 = (0.04f * v) * v;
                const float t2 = 5.0f * v;
                const float dv = (((t1 + t2) + 140.0f) - u) + xt;
                v = v + dv;                          // DT = 1.0 exact
                const float du = a * ((b * v) - u);
                u = u + du;
                const float spike = (v >= 30.0f) ? 1.0f : 0.0f;
                const float oms = 1.0f - spike;
                v = (v * oms) + (c * spike);         // exact, spike in {0,1}
                u = u + (d * spike);
                sf[j] = spike;
            }
            *reinterpret_cast<float4*>(p) = sp;      // spikes in-place
        }

        // ---- transposed read-back + coalesced global stores --------------
        const size_t tb = tile * 512;
#pragma unroll
        for (int k = 0; k < 8; ++k) {
            const float4 o =
                *reinterpret_cast<const float4*>(&L[k * 256 + scat_base]);
            op[tb + k * 64 + lane] = o;
        }
    }
}

extern "C" void kernel_launch(void* const* d_in, const int* in_sizes, int n_in,
                              void* d_out, int out_size, void* d_ws, size_t ws_size,
                              hipStream_t stream) {
    const float* x  = (const float*)d_in[0];
    const float* pa = (const float*)d_in[1];
    const float* pb = (const float*)d_in[2];
    const float* pc = (const float*)d_in[3];
    const float* pd = (const float*)d_in[4];
    float* out = (float*)d_out;

    const int n_neurons = in_sizes[0] / T_STEPS;   // 1,048,576
    const int n_tiles = n_neurons / 64;            // 16384
    const int grid = n_tiles / (WPB * ITERS);      // 1024
    const int stride_tiles = grid * WPB;           // 4096

    izhikevich_kernel<<<grid, TPB, 0, stream>>>(x, pa, pb, pc, pd, out,
                                                stride_tiles);
}